// Round 7
// baseline (237.452 us; speedup 1.0000x reference)
//
#include <hip/hip_runtime.h>

#define BB 4
#define NN 8192
#define QW 8          // queries per wave
#define QB 16         // queries per block (2 query-groups x 8)
#define CAP 64        // survivor capacity per query
#define HALF 4096     // candidates per wave (half of N)
#define HPAIRS 2048   // candidate pairs per half

typedef unsigned long long u64;
typedef unsigned int u32;
typedef float v2f __attribute__((ext_vector_type(2)));

__device__ __forceinline__ u64 shfl_xor_u64(u64 v, int m) {
  u32 lo = (u32)v, hi = (u32)(v >> 32);
  lo = (u32)__shfl_xor((int)lo, m, 64);
  hi = (u32)__shfl_xor((int)hi, m, 64);
  return ((u64)hi << 32) | lo;
}
__device__ __forceinline__ u64 min_u64(u64 a, u64 b) { return a < b ? a : b; }

// fast filter distance: contracted pk math (bounded |d' - d_exact| <= ~1e-5)
__device__ __forceinline__ v2f dist2_fast(float qx, float qy, float qz, float qw,
                                          v2f cx2, v2f cy2, v2f cz2, v2f cw2) {
#pragma clang fp contract(fast)
  return (qw + cw2) - 2.0f * (qx * cx2 + qy * cy2 + qz * cz2);
}

// np-exact distance (matches reference bit-for-bit; fma(-2,..) == t-2*inner exactly)
__device__ __forceinline__ float dist_exact(float4 q, float cx, float cy, float cz, float cw) {
#pragma clang fp contract(off)
  float inner = q.x * cx;
  inner = inner + q.y * cy;
  inner = inner + q.z * cz;
  float tt = q.w + cw;
  return __builtin_fmaf(-2.0f, inner, tt);
}

// ---- fused: zmat (blocks 0..1023, 32-j tiles) + coords prep (blocks 1024..1087) ----
__global__ void fused_prep_zmat(const float* __restrict__ x, const float* __restrict__ W,
                                const float* __restrict__ coords,
                                float* __restrict__ z, float4* __restrict__ c4,
                                float4* __restrict__ cpxy, float4* __restrict__ cpzw,
                                float* __restrict__ ycoords) {
#pragma clang fp contract(off)
  __shared__ float Ws[64 * 65];
  __shared__ float xs[64 * 32];
  int t = threadIdx.x;
  if (blockIdx.x < 1024) {
    int blk = blockIdx.x;
    int b = blk >> 8;                 // 256 blocks per batch
    int j0 = (blk & 255) * 32;
    for (int r = t; r < 4096; r += 256) Ws[(r >> 6) * 65 + (r & 63)] = W[r];
    const float* xb = x + (size_t)b * 64 * NN;
    for (int r = 0; r < 8; ++r) {
      int idx = t + r * 256;
      int c = idx >> 5, j = idx & 31;
      xs[c * 32 + j] = xb[(size_t)c * NN + j0 + j];
    }
    __syncthreads();
    int o = t & 63, jb = (t >> 6) * 8;
    float acc[8];
#pragma unroll
    for (int m = 0; m < 8; ++m) acc[m] = 0.f;
    for (int c = 0; c < 64; ++c) {
      float w = Ws[o * 65 + c];
#pragma unroll
      for (int m = 0; m < 8; ++m) acc[m] = __builtin_fmaf(w, xs[c * 32 + jb + m], acc[m]);
    }
#pragma unroll
    for (int m = 0; m < 8; ++m)
      z[((size_t)b * NN + j0 + jb + m) * 64 + o] = acc[m];
  } else {
    int t2 = (blockIdx.x - 1024) * 256 + t;   // [0, 16384) candidate pairs
    int b = t2 >> 12;
    int pl = t2 & 4095;
    int j0 = 2 * pl;
    const float* cb = coords + (size_t)b * 3 * NN;
    float x0 = cb[j0],          x1 = cb[j0 + 1];
    float y0 = cb[NN + j0],     y1 = cb[NN + j0 + 1];
    float z0 = cb[2 * NN + j0], z1 = cb[2 * NN + j0 + 1];
    float sq0 = (x0 * x0 + y0 * y0) + z0 * z0;   // np-exact sequential fp32
    float sq1 = (x1 * x1 + y1 * y1) + z1 * z1;
    float4 a; a.x = x0; a.y = y0; a.z = z0; a.w = sq0;
    float4 bq; bq.x = x1; bq.y = y1; bq.z = z1; bq.w = sq1;
    c4[(size_t)b * NN + j0] = a;
    c4[(size_t)b * NN + j0 + 1] = bq;
    float4 pxy; pxy.x = x0; pxy.y = x1; pxy.z = y0; pxy.w = y1;
    float4 pzw; pzw.x = z0; pzw.y = z1; pzw.z = sq0; pzw.w = sq1;
    cpxy[(size_t)b * (NN / 2) + pl] = pxy;
    cpzw[(size_t)b * (NN / 2) + pl] = pzw;
#pragma unroll
    for (int r = 0; r < 6; ++r)
      ycoords[r * 16384 + t2] = coords[r * 16384 + t2];  // coords passthrough
  }
}

// ---- KNN: 4 waves = 2 query-groups x 2 candidate-halves; filter + exact select + gather ----
__global__ void __launch_bounds__(256) knn_gather(const float4* __restrict__ c4,
                                                  const float4* __restrict__ cpxy,
                                                  const float4* __restrict__ cpzw,
                                                  const float* __restrict__ z,
                                                  float* __restrict__ y) {
  __shared__ u64 surv[QB][CAP];     // 8 KB
  __shared__ int scnt[QB];
  __shared__ float Tl[QB][2];
  __shared__ int sidx[QB][16];      // 1 KB
  __shared__ float ys[64][QB + 1];  // 4.25 KB
  int t = threadIdx.x;
  int w = t >> 6, lane = t & 63;
  int h = w & 1, g = w >> 1;        // candidate half, query group
  int qbase = blockIdx.x * QB;
  int b = qbase >> 13;
  const float4* cb4 = c4 + (size_t)b * NN;
  const float4* pxy = cpxy + (size_t)b * (NN / 2) + h * HPAIRS;
  const float4* pzw = cpzw + (size_t)b * (NN / 2) + h * HPAIRS;

  if (t < QB) scnt[t] = 0;
  __syncthreads();

  float4 qc[QW];
#pragma unroll
  for (int qi = 0; qi < QW; ++qi) qc[qi] = cb4[(qbase + g * QW + qi) & (NN - 1)];

  // ---- pass A: per-lane min of fast distance over this wave's half ----
  v2f bestd[QW];
#pragma unroll
  for (int qi = 0; qi < QW; ++qi) bestd[qi] = (v2f){3.402823466e+38f, 3.402823466e+38f};

#pragma unroll 2
  for (int s = 0; s < HPAIRS / 64; ++s) {
    float4 cxy = pxy[s * 64 + lane];   // {x0,x1,y0,y1} -> natural v2f register pairs
    float4 czw = pzw[s * 64 + lane];   // {z0,z1,sq0,sq1}
    v2f cx2 = {cxy.x, cxy.y}, cy2 = {cxy.z, cxy.w};
    v2f cz2 = {czw.x, czw.y}, cw2 = {czw.z, czw.w};
#pragma unroll
    for (int qi = 0; qi < QW; ++qi) {
      v2f d2 = dist2_fast(qc[qi].x, qc[qi].y, qc[qi].z, qc[qi].w, cx2, cy2, cz2, cw2);
      bestd[qi].x = fminf(bestd[qi].x, d2.x);
      bestd[qi].y = fminf(bestd[qi].y, d2.y);
    }
  }

  // ---- per-half threshold: 16th smallest of 64 per-lane minima ----
#pragma unroll 1
  for (int qi = 0; qi < QW; ++qi) {
    float v = fminf(bestd[qi].x, bestd[qi].y);
#pragma unroll
    for (int k = 2; k <= 64; k <<= 1) {
#pragma unroll
      for (int jm = k >> 1; jm >= 1; jm >>= 1) {
        float o = __shfl_xor(v, jm, 64);
        bool keepmin = ((lane & jm) == 0) == ((lane & k) == 0);
        v = keepmin ? fminf(v, o) : fmaxf(v, o);
      }
    }
    // BUGFIX R6: __shfl must run with ALL lanes active (ds_bpermute from an
    // inactive source lane is undefined). Hoist out of the lane-0 branch.
    float t16 = __shfl(v, 15, 64);   // ascending: lane 15 = 16th smallest
    if (lane == 0) Tl[g * QW + qi][h] = t16;
  }
  __syncthreads();

  // combined threshold + slack covering contracted-vs-exact rounding (<= ~6e-5)
  float Tf[QW];
#pragma unroll
  for (int qi = 0; qi < QW; ++qi) {
    float T = fminf(Tl[g * QW + qi][0], Tl[g * QW + qi][1]);
    Tf[qi] = T * 1.000001f + 1e-3f;
  }

  // ---- pass B: filter with fast d, exact recompute only for survivors ----
#pragma unroll 1
  for (int s = 0; s < HPAIRS / 64; ++s) {
    float4 cxy = pxy[s * 64 + lane];
    float4 czw = pzw[s * 64 + lane];
    v2f cx2 = {cxy.x, cxy.y}, cy2 = {cxy.z, cxy.w};
    v2f cz2 = {czw.x, czw.y}, cw2 = {czw.z, czw.w};
    int j0 = h * HALF + (s * 64 + lane) * 2;
#pragma unroll
    for (int qi = 0; qi < QW; ++qi) {
      v2f d2 = dist2_fast(qc[qi].x, qc[qi].y, qc[qi].z, qc[qi].w, cx2, cy2, cz2, cw2);
      int ql = g * QW + qi;
      if (d2.x <= Tf[qi]) {
        float de = dist_exact(qc[qi], cxy.x, cxy.z, czw.x, czw.z);
        u32 f = __float_as_uint(de);
        u32 m32 = f ^ ((u32)(((int)f) >> 31) | 0x80000000u);
        int pos = atomicAdd(&scnt[ql], 1);
        if (pos < CAP) surv[ql][pos] = ((u64)m32 << 32) | (u32)j0;
      }
      if (d2.y <= Tf[qi]) {
        float de = dist_exact(qc[qi], cxy.y, cxy.w, czw.y, czw.w);
        u32 f = __float_as_uint(de);
        u32 m32 = f ^ ((u32)(((int)f) >> 31) | 0x80000000u);
        int pos = atomicAdd(&scnt[ql], 1);
        if (pos < CAP) surv[ql][pos] = ((u64)m32 << 32) | (u32)(j0 + 1);
      }
    }
  }
  __syncthreads();

  // ---- exact top-16 per query (u64 bitonic over merged survivors), then gather ----
  const float* zb = z + (size_t)b * NN * 64;
#pragma unroll 1
  for (int u = 0; u < 4; ++u) {
    int ql = w * 4 + u;                 // each wave owns 4 queries for select+gather
    int n = scnt[ql]; if (n > CAP) n = CAP;
    u64 v = (lane < n) ? surv[ql][lane] : ~0ull;
#pragma unroll
    for (int k = 2; k <= 64; k <<= 1) {
#pragma unroll
      for (int jm = k >> 1; jm >= 1; jm >>= 1) {
        u64 o = shfl_xor_u64(v, jm);
        bool keepmin = ((lane & jm) == 0) == ((lane & k) == 0);
        u64 mn = min_u64(v, o);
        u64 mx = (v < o) ? o : v;
        v = keepmin ? mn : mx;
      }
    }
    if (lane < 16) sidx[ql][lane] = (int)(v & 0xFFFFFFFFull);
  }
#pragma unroll 1
  for (int u = 0; u < 4; ++u) {
    int ql = w * 4 + u;
    const int* id = sidx[ql];           // same-wave LDS, no barrier needed
    float m = -3.402823466e+38f;
#pragma unroll
    for (int k = 0; k < 16; ++k)
      m = fmaxf(m, zb[(size_t)id[k] * 64 + lane]);   // coalesced 256B row
    ys[lane][ql] = m;
  }
  __syncthreads();
  int i0 = qbase & (NN - 1);
#pragma unroll
  for (int r = 0; r < 4; ++r) {
    int e = r * 256 + t;
    int o = e >> 4, ql = e & 15;
    y[((size_t)b * 64 + o) * NN + i0 + ql] = ys[o][ql];
  }
}

extern "C" void kernel_launch(void* const* d_in, const int* in_sizes, int n_in,
                              void* d_out, int out_size, void* d_ws, size_t ws_size,
                              hipStream_t stream) {
  const float* x      = (const float*)d_in[0];   // [B,64,N]
  const float* coords = (const float*)d_in[1];   // [B,3,N]
  const float* W      = (const float*)d_in[2];   // [64,64]
  float* y = (float*)d_out;                      // [B,64,N] then coords

  char* ws = (char*)d_ws;
  float4* c4   = (float4*)ws;                              // 512 KB
  float4* cpxy = (float4*)(ws + (1u << 19));               // 256 KB
  float4* cpzw = (float4*)(ws + (1u << 19) + (1u << 18));  // 256 KB
  float*  z    = (float*)(ws + (1u << 20));                // 8 MB

  float* ycoords = y + (size_t)BB * 64 * NN;

  fused_prep_zmat<<<1024 + 64, 256, 0, stream>>>(x, W, coords, z, c4, cpxy, cpzw, ycoords);
  knn_gather<<<BB * NN / QB, 256, 0, stream>>>(c4, cpxy, cpzw, z, y);
}